// Round 4
// baseline (92.735 us; speedup 1.0000x reference)
//
#include <hip/hip_runtime.h>
#include <hip/hip_bf16.h>
#include <stdint.h>

#define B 16
#define NN 2048
#define DIM 256
#define SZ 16384
#define TOPK 50
#define NCHUNK 32
#define CHUNK (NN / NCHUNK)  // 64

// ws layout (float offsets)
#define OFF_MEANB   0         // [B][DIM]
#define OFF_STDB    4096      // [B][DIM]
#define OFF_PSUM    8192      // [B][NCHUNK][DIM]
#define OFF_PSUMSQ  139264    // [B][NCHUNK][DIM]
#define OFF_DS      270336    // [B][SZ]
#define OFF_A       534528    // [B][DIM]
#define OFF_C       538624    // [B][DIM]

__global__ __launch_bounds__(256) void k_partial(const float* __restrict__ x,
                                                 float* __restrict__ ws) {
    int b = blockIdx.y, c = blockIdx.x;
    int t = threadIdx.x;
    int rs = t >> 6, col = t & 63;
    const float4* p = (const float4*)x + ((size_t)(b * NN + c * CHUNK + rs)) * 64 + col;
    float4 s = {0.f, 0.f, 0.f, 0.f}, q = {0.f, 0.f, 0.f, 0.f};
#pragma unroll 4
    for (int n = 0; n < CHUNK / 4; n++) {
        float4 v = p[(size_t)n * 256];
        s.x += v.x; s.y += v.y; s.z += v.z; s.w += v.w;
        q.x += v.x * v.x; q.y += v.y * v.y; q.z += v.z * v.z; q.w += v.w * v.w;
    }
    __shared__ float4 ss[4][64], qq[4][64];
    ss[rs][col] = s; qq[rs][col] = q;
    __syncthreads();
    if (t < 64) {
        float4 S = ss[0][t], Q = qq[0][t];
#pragma unroll
        for (int r = 1; r < 4; r++) {
            float4 a = ss[r][t], b2 = qq[r][t];
            S.x += a.x; S.y += a.y; S.z += a.z; S.w += a.w;
            Q.x += b2.x; Q.y += b2.y; Q.z += b2.z; Q.w += b2.w;
        }
        ((float4*)(ws + OFF_PSUM))[(b * NCHUNK + c) * 64 + t] = S;
        ((float4*)(ws + OFF_PSUMSQ))[(b * NCHUNK + c) * 64 + t] = Q;
    }
}

__global__ __launch_bounds__(256) void k_finalize(float* __restrict__ ws) {
    int b = blockIdx.x, d = threadIdx.x;
    float s = 0.f, q = 0.f;
#pragma unroll
    for (int c = 0; c < NCHUNK; c++) {
        s += ws[OFF_PSUM + (b * NCHUNK + c) * DIM + d];
        q += ws[OFF_PSUMSQ + (b * NCHUNK + c) * DIM + d];
    }
    float mean = s * (1.f / NN);
    float var = q * (1.f / NN) - mean * mean;
    float sd = sqrtf(fmaxf(var, 0.f));
    ws[OFF_MEANB + b * DIM + d] = mean;
    ws[OFF_STDB + b * DIM + d] = sd;
}

#define RS_STEP(half)                                                   \
    {                                                                   \
        bool hi = (sub & half) != 0;                                    \
        _Pragma("unroll")                                               \
        for (int j = 0; j < half; j++) {                                \
            float send = hi ? am[j] : am[j + half];                     \
            float keep = hi ? am[j + half] : am[j];                     \
            am[j] = keep + __shfl_xor(send, half, 16);                  \
            send = hi ? as[j] : as[j + half];                           \
            keep = hi ? as[j + half] : as[j];                           \
            as[j] = keep + __shfl_xor(send, half, 16);                  \
        }                                                               \
    }

__global__ __launch_bounds__(256) void k_dist(const float* __restrict__ means,
                                              const float* __restrict__ stds,
                                              float* __restrict__ ws) {
    __shared__ float4 lm[16 * 64], ls[16 * 64];
    int tid = threadIdx.x;
    const float4* gm = (const float4*)(ws + OFF_MEANB);
    const float4* gs = (const float4*)(ws + OFF_STDB);
#pragma unroll
    for (int i = 0; i < 4; i++) {
        lm[i * 256 + tid] = gm[i * 256 + tid];
        ls[i * 256 + tid] = gs[i * 256 + tid];
    }
    __syncthreads();
    int lane = tid & 63, wid = tid >> 6;
    int sub = lane & 15, eg = lane >> 4;
    int e = blockIdx.x * 16 + wid * 4 + eg;
    const float4* mrow = (const float4*)means + (size_t)e * 64;
    const float4* srow = (const float4*)stds + (size_t)e * 64;
    float4 m[4], s[4];
#pragma unroll
    for (int k = 0; k < 4; k++) {
        m[k] = mrow[k * 16 + sub];
        s[k] = srow[k * 16 + sub];
    }
    float am[16], as[16];
#pragma unroll
    for (int b = 0; b < 16; b++) {
        float accm = 0.f, accs = 0.f;
#pragma unroll
        for (int k = 0; k < 4; k++) {
            float4 q = lm[b * 64 + k * 16 + sub];
            float dx = m[k].x - q.x, dy = m[k].y - q.y;
            float dz = m[k].z - q.z, dw = m[k].w - q.w;
            accm += dx * dx + dy * dy + dz * dz + dw * dw;
            q = ls[b * 64 + k * 16 + sub];
            dx = s[k].x - q.x; dy = s[k].y - q.y;
            dz = s[k].z - q.z; dw = s[k].w - q.w;
            accs += dx * dx + dy * dy + dz * dz + dw * dw;
        }
        am[b] = accm; as[b] = accs;
    }
    RS_STEP(8)
    RS_STEP(4)
    RS_STEP(2)
    RS_STEP(1)
    ws[OFF_DS + sub * SZ + e] = sqrtf(am[0]) + sqrtf(as[0]);
}

// fused top-k + goal: one block per batch, streaming passes over ds (L2-hot),
// no per-thread arrays -> no scratch spill.
__global__ __launch_bounds__(256) void k_topkgoal(const float* __restrict__ means,
                                                  const float* __restrict__ stds,
                                                  const float* __restrict__ t1p,
                                                  const float* __restrict__ t2p,
                                                  float* __restrict__ ws) {
    int b = blockIdx.x, tid = threadIdx.x;
    const float* ds = ws + OFF_DS + b * SZ;
    __shared__ float red[256];
    __shared__ int hist[256], cum[256];
    __shared__ float sh_lo, sh_sc;
    __shared__ int sh_T, sh_cnt;
    __shared__ float candV[1024];
    __shared__ int candI[1024];
    __shared__ float topd_sh[TOPK];
    __shared__ int topi_sh[TOPK];
    __shared__ float w_sh[TOPK];

    // pass 1: min/max
    float mn = 1e30f, mx = -1e30f;
    for (int i = tid; i < SZ; i += 256) {
        float v = ds[i];
        mn = fminf(mn, v);
        mx = fmaxf(mx, v);
    }
    red[tid] = mn;
    __syncthreads();
    for (int off = 128; off > 0; off >>= 1) {
        if (tid < off) red[tid] = fminf(red[tid], red[tid + off]);
        __syncthreads();
    }
    if (tid == 0) sh_lo = red[0];
    __syncthreads();
    red[tid] = mx;
    __syncthreads();
    for (int off = 128; off > 0; off >>= 1) {
        if (tid < off) red[tid] = fmaxf(red[tid], red[tid + off]);
        __syncthreads();
    }
    if (tid == 0) {
        sh_sc = 255.0f / fmaxf(red[0] - sh_lo, 1e-20f);
        sh_cnt = 0;
    }
    hist[tid] = 0;
    __syncthreads();

    // pass 2: histogram
    float lo = sh_lo, sc = sh_sc;
    for (int i = tid; i < SZ; i += 256) {
        int bi = (int)((ds[i] - lo) * sc);
        atomicAdd(&hist[min(max(bi, 0), 255)], 1);
    }
    __syncthreads();

    cum[tid] = hist[tid];
    __syncthreads();
    for (int off = 1; off < 256; off <<= 1) {
        int t2 = (tid >= off) ? cum[tid - off] : 0;
        __syncthreads();
        cum[tid] += t2;
        __syncthreads();
    }
    if (cum[tid] >= TOPK && (tid == 0 || cum[tid - 1] < TOPK)) sh_T = tid;
    __syncthreads();
    int T = sh_T;

    // pass 3: collect candidates
    for (int i = tid; i < SZ; i += 256) {
        float v = ds[i];
        int bi = min(max((int)((v - lo) * sc), 0), 255);
        if (bi <= T) {
            int p = atomicAdd(&sh_cnt, 1);
            if (p < 1024) { candV[p] = v; candI[p] = i; }
        }
    }
    __syncthreads();
    int cnt = min(sh_cnt, 1024);

    // exact parallel rank-count selection (key = (bits<<32)|idx, ties -> lowest idx)
    for (int p = tid; p < cnt; p += 256) {
        unsigned long long kp =
            ((unsigned long long)__float_as_uint(candV[p]) << 32) | (unsigned int)candI[p];
        int rank = 0;
        for (int q = 0; q < cnt; q++) {
            unsigned long long kq =
                ((unsigned long long)__float_as_uint(candV[q]) << 32) | (unsigned int)candI[q];
            rank += (kq < kp) ? 1 : 0;
        }
        if (rank < TOPK) {
            topd_sh[rank] = candV[p];
            topi_sh[rank] = candI[p];
        }
    }
    __syncthreads();

    // softmax(exp(-t1*d)) exactly as reference (double exponential)
    float t1 = t1p[0], t2 = t2p[0];
    if (tid < 64) {
        float sv = (tid < TOPK) ? expf(-t1 * topd_sh[tid]) : -1e30f;
        float m = sv;
#pragma unroll
        for (int off = 32; off > 0; off >>= 1) m = fmaxf(m, __shfl_xor(m, off, 64));
        float e = (tid < TOPK) ? expf(sv - m) : 0.f;
        float sum = e;
#pragma unroll
        for (int off = 32; off > 0; off >>= 1) sum += __shfl_xor(sum, off, 64);
        if (tid < TOPK) w_sh[tid] = e / sum;
    }
    __syncthreads();

    // gather + affine coefficients
    int d = tid;
    float mg = 0.f, sg = 0.f;
#pragma unroll 5
    for (int r = 0; r < TOPK; r++) {
        float w = w_sh[r];
        int idx = topi_sh[r];
        mg += w * means[(size_t)idx * DIM + d];
        sg += w * stds[(size_t)idx * DIM + d];
    }
    float mean = ws[OFF_MEANB + b * DIM + d];
    float sd = ws[OFF_STDB + b * DIM + d];
    float lerp = 1.f / (1.f + expf(-t2));
    float mf = lerp * mg + (1.f - lerp) * mean;
    float sf = lerp * sg + (1.f - lerp) * sd;
    float A = sf / sd;
    float C = mf - A * mean;
    ws[OFF_A + b * DIM + d] = A;
    ws[OFF_C + b * DIM + d] = C;
}

__global__ __launch_bounds__(256) void k_apply(const float* __restrict__ x,
                                               const float* __restrict__ ws,
                                               float* __restrict__ out) {
    int f4 = blockIdx.x * 256 + threadIdx.x;
    int b = f4 >> 17;
    int d4 = f4 & 63;
    float4 xv = ((const float4*)x)[f4];
    float4 a = ((const float4*)(ws + OFF_A))[b * 64 + d4];
    float4 c = ((const float4*)(ws + OFF_C))[b * 64 + d4];
    float4 o;
    o.x = fmaf(a.x, xv.x, c.x);
    o.y = fmaf(a.y, xv.y, c.y);
    o.z = fmaf(a.z, xv.z, c.z);
    o.w = fmaf(a.w, xv.w, c.w);
    ((float4*)out)[f4] = o;
}

extern "C" void kernel_launch(void* const* d_in, const int* in_sizes, int n_in,
                              void* d_out, int out_size, void* d_ws, size_t ws_size,
                              hipStream_t stream) {
    const float* x = (const float*)d_in[0];
    const float* means = (const float*)d_in[1];
    const float* stds = (const float*)d_in[2];
    const float* t1 = (const float*)d_in[3];
    const float* t2 = (const float*)d_in[4];
    float* out = (float*)d_out;
    float* ws = (float*)d_ws;

    k_partial<<<dim3(NCHUNK, B), 256, 0, stream>>>(x, ws);
    k_finalize<<<B, 256, 0, stream>>>(ws);
    k_dist<<<SZ / 16, 256, 0, stream>>>(means, stds, ws);
    k_topkgoal<<<B, 256, 0, stream>>>(means, stds, t1, t2, ws);
    k_apply<<<(B * NN * DIM / 4) / 256, 256, 0, stream>>>(x, ws, out);
}

// Round 5
// 65.455 us; speedup vs baseline: 1.4168x; 1.4168x over previous
//
#include <hip/hip_runtime.h>
#include <hip/hip_bf16.h>
#include <stdint.h>

#define B 16
#define NN 2048
#define DIM 256
#define SZ 16384
#define TOPK 50
#define NCHUNK 32
#define CHUNK (NN / NCHUNK)  // 64

// ws layout (float offsets)
#define OFF_MEANB   0         // [B][DIM]
#define OFF_STDB    4096      // [B][DIM]
#define OFF_PSUM    8192      // [B][NCHUNK][DIM]
#define OFF_PSUMSQ  139264    // [B][NCHUNK][DIM]
#define OFF_DS      270336    // [B][SZ]
#define OFF_A       534528    // [B][DIM]
#define OFF_C       538624    // [B][DIM]

__global__ __launch_bounds__(256) void k_partial(const float* __restrict__ x,
                                                 float* __restrict__ ws) {
    int b = blockIdx.y, c = blockIdx.x;
    int t = threadIdx.x;
    int rs = t >> 6, col = t & 63;
    const float4* p = (const float4*)x + ((size_t)(b * NN + c * CHUNK + rs)) * 64 + col;
    float4 s = {0.f, 0.f, 0.f, 0.f}, q = {0.f, 0.f, 0.f, 0.f};
#pragma unroll 4
    for (int n = 0; n < CHUNK / 4; n++) {
        float4 v = p[(size_t)n * 256];
        s.x += v.x; s.y += v.y; s.z += v.z; s.w += v.w;
        q.x += v.x * v.x; q.y += v.y * v.y; q.z += v.z * v.z; q.w += v.w * v.w;
    }
    __shared__ float4 ss[4][64], qq[4][64];
    ss[rs][col] = s; qq[rs][col] = q;
    __syncthreads();
    if (t < 64) {
        float4 S = ss[0][t], Q = qq[0][t];
#pragma unroll
        for (int r = 1; r < 4; r++) {
            float4 a = ss[r][t], b2 = qq[r][t];
            S.x += a.x; S.y += a.y; S.z += a.z; S.w += a.w;
            Q.x += b2.x; Q.y += b2.y; Q.z += b2.z; Q.w += b2.w;
        }
        ((float4*)(ws + OFF_PSUM))[(b * NCHUNK + c) * 64 + t] = S;
        ((float4*)(ws + OFF_PSUMSQ))[(b * NCHUNK + c) * 64 + t] = Q;
    }
}

__global__ __launch_bounds__(256) void k_finalize(float* __restrict__ ws) {
    int b = blockIdx.x, d = threadIdx.x;
    float s = 0.f, q = 0.f;
#pragma unroll
    for (int c = 0; c < NCHUNK; c++) {
        s += ws[OFF_PSUM + (b * NCHUNK + c) * DIM + d];
        q += ws[OFF_PSUMSQ + (b * NCHUNK + c) * DIM + d];
    }
    float mean = s * (1.f / NN);
    float var = q * (1.f / NN) - mean * mean;
    float sd = sqrtf(fmaxf(var, 0.f));
    ws[OFF_MEANB + b * DIM + d] = mean;
    ws[OFF_STDB + b * DIM + d] = sd;
}

#define RS_STEP(half)                                                   \
    {                                                                   \
        bool hi = (sub & half) != 0;                                    \
        _Pragma("unroll")                                               \
        for (int j = 0; j < half; j++) {                                \
            float send = hi ? am[j] : am[j + half];                     \
            float keep = hi ? am[j + half] : am[j];                     \
            am[j] = keep + __shfl_xor(send, half, 16);                  \
            send = hi ? as[j] : as[j + half];                           \
            keep = hi ? as[j + half] : as[j];                           \
            as[j] = keep + __shfl_xor(send, half, 16);                  \
        }                                                               \
    }

__global__ __launch_bounds__(256) void k_dist(const float* __restrict__ means,
                                              const float* __restrict__ stds,
                                              float* __restrict__ ws) {
    __shared__ float4 lm[16 * 64], ls[16 * 64];
    int tid = threadIdx.x;
    const float4* gm = (const float4*)(ws + OFF_MEANB);
    const float4* gs = (const float4*)(ws + OFF_STDB);
#pragma unroll
    for (int i = 0; i < 4; i++) {
        lm[i * 256 + tid] = gm[i * 256 + tid];
        ls[i * 256 + tid] = gs[i * 256 + tid];
    }
    __syncthreads();
    int lane = tid & 63, wid = tid >> 6;
    int sub = lane & 15, eg = lane >> 4;
    int e = blockIdx.x * 16 + wid * 4 + eg;
    const float4* mrow = (const float4*)means + (size_t)e * 64;
    const float4* srow = (const float4*)stds + (size_t)e * 64;
    float4 m[4], s[4];
#pragma unroll
    for (int k = 0; k < 4; k++) {
        m[k] = mrow[k * 16 + sub];
        s[k] = srow[k * 16 + sub];
    }
    float am[16], as[16];
#pragma unroll
    for (int b = 0; b < 16; b++) {
        float accm = 0.f, accs = 0.f;
#pragma unroll
        for (int k = 0; k < 4; k++) {
            float4 q = lm[b * 64 + k * 16 + sub];
            float dx = m[k].x - q.x, dy = m[k].y - q.y;
            float dz = m[k].z - q.z, dw = m[k].w - q.w;
            accm += dx * dx + dy * dy + dz * dz + dw * dw;
            q = ls[b * 64 + k * 16 + sub];
            dx = s[k].x - q.x; dy = s[k].y - q.y;
            dz = s[k].z - q.z; dw = s[k].w - q.w;
            accs += dx * dx + dy * dy + dz * dz + dw * dw;
        }
        am[b] = accm; as[b] = accs;
    }
    RS_STEP(8)
    RS_STEP(4)
    RS_STEP(2)
    RS_STEP(1)
    ws[OFF_DS + sub * SZ + e] = sqrtf(am[0]) + sqrtf(as[0]);
}

// fused top-k + goal: 1024 threads, values in registers, two-level histogram
__global__ __launch_bounds__(1024) void k_topkgoal(const float* __restrict__ means,
                                                   const float* __restrict__ stds,
                                                   const float* __restrict__ t1p,
                                                   const float* __restrict__ t2p,
                                                   float* __restrict__ ws) {
    int b = blockIdx.x, tid = threadIdx.x;
    int lane = tid & 63, wid = tid >> 6;  // 16 waves
    const float4* ds4 = (const float4*)(ws + OFF_DS + b * SZ);

    __shared__ float wmn[16], wmx[16];
    __shared__ int hist[256], cum[256], hist2[256], cum2[256];
    __shared__ float sh_lo, sh_sc;
    __shared__ int sh_T, sh_below, sh_T2, sh_cnt;
    __shared__ unsigned long long candK[512];
    __shared__ float topd_sh[TOPK];
    __shared__ int topi_sh[TOPK];
    __shared__ float w_sh[TOPK];
    __shared__ float mgp[4][256], sgp[4][256];

    // single global pass: 16 values per thread in registers
    float v[16];
    {
        float4 t0 = ds4[tid], t1 = ds4[tid + 1024], t2 = ds4[tid + 2048], t3 = ds4[tid + 3072];
        v[0] = t0.x; v[1] = t0.y; v[2] = t0.z; v[3] = t0.w;
        v[4] = t1.x; v[5] = t1.y; v[6] = t1.z; v[7] = t1.w;
        v[8] = t2.x; v[9] = t2.y; v[10] = t2.z; v[11] = t2.w;
        v[12] = t3.x; v[13] = t3.y; v[14] = t3.z; v[15] = t3.w;
    }

    float mn = v[0], mx = v[0];
#pragma unroll
    for (int i = 1; i < 16; i++) { mn = fminf(mn, v[i]); mx = fmaxf(mx, v[i]); }
#pragma unroll
    for (int off = 32; off > 0; off >>= 1) {
        mn = fminf(mn, __shfl_xor(mn, off, 64));
        mx = fmaxf(mx, __shfl_xor(mx, off, 64));
    }
    if (lane == 0) { wmn[wid] = mn; wmx[wid] = mx; }
    if (tid < 256) { hist[tid] = 0; hist2[tid] = 0; }
    if (tid == 0) sh_cnt = 0;
    __syncthreads();
    if (tid == 0) {
        float l = wmn[0], h = wmx[0];
#pragma unroll
        for (int i = 1; i < 16; i++) { l = fminf(l, wmn[i]); h = fmaxf(h, wmx[i]); }
        sh_lo = l;
        sh_sc = 255.0f / fmaxf(h - l, 1e-20f);
    }
    __syncthreads();
    float lo = sh_lo, sc = sh_sc;

    // coarse histogram (bins kept in registers)
    int bn[16];
#pragma unroll
    for (int i = 0; i < 16; i++) {
        bn[i] = min(max((int)((v[i] - lo) * sc), 0), 255);
        atomicAdd(&hist[bn[i]], 1);
    }
    __syncthreads();
    if (tid < 256) cum[tid] = hist[tid];
    __syncthreads();
    for (int off = 1; off < 256; off <<= 1) {
        int t2 = 0;
        if (tid < 256 && tid >= off) t2 = cum[tid - off];
        __syncthreads();
        if (tid < 256) cum[tid] += t2;
        __syncthreads();
    }
    if (tid < 256 && cum[tid] >= TOPK && (tid == 0 || cum[tid - 1] < TOPK)) {
        sh_T = tid;
        sh_below = (tid == 0) ? 0 : cum[tid - 1];
    }
    __syncthreads();
    int T = sh_T, below = sh_below;

    // fine histogram inside boundary bin T
    float flo = lo + (float)T / sc;
    float fsc = sc * 255.0f;
    int fb[16];
#pragma unroll
    for (int i = 0; i < 16; i++) {
        if (bn[i] == T) {
            fb[i] = min(max((int)((v[i] - flo) * fsc), 0), 255);
            atomicAdd(&hist2[fb[i]], 1);
        } else {
            fb[i] = 256;
        }
    }
    __syncthreads();
    if (tid < 256) cum2[tid] = hist2[tid];
    __syncthreads();
    for (int off = 1; off < 256; off <<= 1) {
        int t2 = 0;
        if (tid < 256 && tid >= off) t2 = cum2[tid - off];
        __syncthreads();
        if (tid < 256) cum2[tid] += t2;
        __syncthreads();
    }
    int need = TOPK - below;
    if (tid < 256 && cum2[tid] >= need && (tid == 0 || cum2[tid - 1] < need)) sh_T2 = tid;
    __syncthreads();
    int T2 = sh_T2;

    // collect candidates (value-prefix set, >= 50 elems, ~50-70 expected)
#pragma unroll
    for (int i = 0; i < 16; i++) {
        if (bn[i] < T || (bn[i] == T && fb[i] <= T2)) {
            int p = atomicAdd(&sh_cnt, 1);
            if (p < 512) {
                int idx = 4 * (tid + (i >> 2) * 1024) + (i & 3);
                candK[p] = ((unsigned long long)__float_as_uint(v[i]) << 32) | (unsigned int)idx;
            }
        }
    }
    __syncthreads();
    int cnt = min(sh_cnt, 512);

    // exact rank-count selection (key ties -> lowest index, matches jax)
    for (int p = tid; p < cnt; p += 1024) {
        unsigned long long kp = candK[p];
        int rank = 0;
        for (int q = 0; q < cnt; q++) rank += (candK[q] < kp) ? 1 : 0;
        if (rank < TOPK) {
            topd_sh[rank] = __uint_as_float((unsigned int)(kp >> 32));
            topi_sh[rank] = (int)(kp & 0xffffffffu);
        }
    }
    __syncthreads();

    // softmax(exp(-t1*d)) — exact double-exponential semantics
    float t1 = t1p[0], t2v = t2p[0];
    if (tid < 64) {
        float sv = (tid < TOPK) ? expf(-t1 * topd_sh[tid]) : -1e30f;
        float m = sv;
#pragma unroll
        for (int off = 32; off > 0; off >>= 1) m = fmaxf(m, __shfl_xor(m, off, 64));
        float e = (tid < TOPK) ? expf(sv - m) : 0.f;
        float sum = e;
#pragma unroll
        for (int off = 32; off > 0; off >>= 1) sum += __shfl_xor(sum, off, 64);
        if (tid < TOPK) w_sh[tid] = e / sum;
    }
    __syncthreads();

    // gather with all 16 waves: TOPK split across 4 quarters
    int d = tid & 255, qd = tid >> 8;
    float mg = 0.f, sg = 0.f;
    for (int r = qd; r < TOPK; r += 4) {
        float w = w_sh[r];
        int idx = topi_sh[r];
        mg += w * means[(size_t)idx * DIM + d];
        sg += w * stds[(size_t)idx * DIM + d];
    }
    mgp[qd][d] = mg; sgp[qd][d] = sg;
    __syncthreads();
    if (tid < 256) {
        float MG = mgp[0][tid] + mgp[1][tid] + mgp[2][tid] + mgp[3][tid];
        float SG = sgp[0][tid] + sgp[1][tid] + sgp[2][tid] + sgp[3][tid];
        float mean = ws[OFF_MEANB + b * DIM + tid];
        float sd = ws[OFF_STDB + b * DIM + tid];
        float lerp = 1.f / (1.f + expf(-t2v));
        float mf = lerp * MG + (1.f - lerp) * mean;
        float sf = lerp * SG + (1.f - lerp) * sd;
        float A = sf / sd;
        float C = mf - A * mean;
        ws[OFF_A + b * DIM + tid] = A;
        ws[OFF_C + b * DIM + tid] = C;
    }
}

__global__ __launch_bounds__(256) void k_apply(const float* __restrict__ x,
                                               const float* __restrict__ ws,
                                               float* __restrict__ out) {
    int f4 = blockIdx.x * 256 + threadIdx.x;
    int b = f4 >> 17;
    int d4 = f4 & 63;
    float4 xv = ((const float4*)x)[f4];
    float4 a = ((const float4*)(ws + OFF_A))[b * 64 + d4];
    float4 c = ((const float4*)(ws + OFF_C))[b * 64 + d4];
    float4 o;
    o.x = fmaf(a.x, xv.x, c.x);
    o.y = fmaf(a.y, xv.y, c.y);
    o.z = fmaf(a.z, xv.z, c.z);
    o.w = fmaf(a.w, xv.w, c.w);
    ((float4*)out)[f4] = o;
}

extern "C" void kernel_launch(void* const* d_in, const int* in_sizes, int n_in,
                              void* d_out, int out_size, void* d_ws, size_t ws_size,
                              hipStream_t stream) {
    const float* x = (const float*)d_in[0];
    const float* means = (const float*)d_in[1];
    const float* stds = (const float*)d_in[2];
    const float* t1 = (const float*)d_in[3];
    const float* t2 = (const float*)d_in[4];
    float* out = (float*)d_out;
    float* ws = (float*)d_ws;

    k_partial<<<dim3(NCHUNK, B), 256, 0, stream>>>(x, ws);
    k_finalize<<<B, 256, 0, stream>>>(ws);
    k_dist<<<SZ / 16, 256, 0, stream>>>(means, stds, ws);
    k_topkgoal<<<B, 1024, 0, stream>>>(means, stds, t1, t2, ws);
    k_apply<<<(B * NN * DIM / 4) / 256, 256, 0, stream>>>(x, ws, out);
}

// Round 6
// 63.796 us; speedup vs baseline: 1.4536x; 1.0260x over previous
//
#include <hip/hip_runtime.h>
#include <hip/hip_bf16.h>
#include <stdint.h>

#define B 16
#define NN 2048
#define DIM 256
#define SZ 16384
#define TOPK 50
#define NCHUNK 32
#define CHUNK (NN / NCHUNK)  // 64

// ws layout (float offsets)
#define OFF_MEANB   0         // [B][DIM]
#define OFF_STDB    4096      // [B][DIM]
#define OFF_PSUM    8192      // [B][NCHUNK][DIM]
#define OFF_PSUMSQ  139264    // [B][NCHUNK][DIM]
#define OFF_DS      270336    // [B][SZ]
#define OFF_A       534528    // [B][DIM]
#define OFF_C       538624    // [B][DIM]

__global__ __launch_bounds__(256) void k_partial(const float* __restrict__ x,
                                                 float* __restrict__ ws) {
    int b = blockIdx.y, c = blockIdx.x;
    int t = threadIdx.x;
    int rs = t >> 6, col = t & 63;
    const float4* p = (const float4*)x + ((size_t)(b * NN + c * CHUNK + rs)) * 64 + col;
    float4 s = {0.f, 0.f, 0.f, 0.f}, q = {0.f, 0.f, 0.f, 0.f};
#pragma unroll 4
    for (int n = 0; n < CHUNK / 4; n++) {
        float4 v = p[(size_t)n * 256];
        s.x += v.x; s.y += v.y; s.z += v.z; s.w += v.w;
        q.x += v.x * v.x; q.y += v.y * v.y; q.z += v.z * v.z; q.w += v.w * v.w;
    }
    __shared__ float4 ss[4][64], qq[4][64];
    ss[rs][col] = s; qq[rs][col] = q;
    __syncthreads();
    if (t < 64) {
        float4 S = ss[0][t], Q = qq[0][t];
#pragma unroll
        for (int r = 1; r < 4; r++) {
            float4 a = ss[r][t], b2 = qq[r][t];
            S.x += a.x; S.y += a.y; S.z += a.z; S.w += a.w;
            Q.x += b2.x; Q.y += b2.y; Q.z += b2.z; Q.w += b2.w;
        }
        ((float4*)(ws + OFF_PSUM))[(b * NCHUNK + c) * 64 + t] = S;
        ((float4*)(ws + OFF_PSUMSQ))[(b * NCHUNK + c) * 64 + t] = Q;
    }
}

__global__ __launch_bounds__(256) void k_finalize(float* __restrict__ ws) {
    int b = blockIdx.x, d = threadIdx.x;
    float s = 0.f, q = 0.f;
#pragma unroll
    for (int c = 0; c < NCHUNK; c++) {
        s += ws[OFF_PSUM + (b * NCHUNK + c) * DIM + d];
        q += ws[OFF_PSUMSQ + (b * NCHUNK + c) * DIM + d];
    }
    float mean = s * (1.f / NN);
    float var = q * (1.f / NN) - mean * mean;
    float sd = sqrtf(fmaxf(var, 0.f));
    ws[OFF_MEANB + b * DIM + d] = mean;
    ws[OFF_STDB + b * DIM + d] = sd;
}

#define RS_STEP(half)                                                   \
    {                                                                   \
        bool hi = (sub & half) != 0;                                    \
        _Pragma("unroll")                                               \
        for (int j = 0; j < half; j++) {                                \
            float send = hi ? am[j] : am[j + half];                     \
            float keep = hi ? am[j + half] : am[j];                     \
            am[j] = keep + __shfl_xor(send, half, 16);                  \
            send = hi ? as[j] : as[j + half];                           \
            keep = hi ? as[j + half] : as[j];                           \
            as[j] = keep + __shfl_xor(send, half, 16);                  \
        }                                                               \
    }

__global__ __launch_bounds__(256) void k_dist(const float* __restrict__ means,
                                              const float* __restrict__ stds,
                                              float* __restrict__ ws) {
    __shared__ float4 lm[16 * 64], ls[16 * 64];
    int tid = threadIdx.x;
    const float4* gm = (const float4*)(ws + OFF_MEANB);
    const float4* gs = (const float4*)(ws + OFF_STDB);
#pragma unroll
    for (int i = 0; i < 4; i++) {
        lm[i * 256 + tid] = gm[i * 256 + tid];
        ls[i * 256 + tid] = gs[i * 256 + tid];
    }
    __syncthreads();
    int lane = tid & 63, wid = tid >> 6;
    int sub = lane & 15, eg = lane >> 4;
    int e = blockIdx.x * 16 + wid * 4 + eg;
    const float4* mrow = (const float4*)means + (size_t)e * 64;
    const float4* srow = (const float4*)stds + (size_t)e * 64;
    float4 m[4], s[4];
#pragma unroll
    for (int k = 0; k < 4; k++) {
        m[k] = mrow[k * 16 + sub];
        s[k] = srow[k * 16 + sub];
    }
    float am[16], as[16];
#pragma unroll
    for (int b = 0; b < 16; b++) {
        float accm = 0.f, accs = 0.f;
#pragma unroll
        for (int k = 0; k < 4; k++) {
            float4 q = lm[b * 64 + k * 16 + sub];
            float dx = m[k].x - q.x, dy = m[k].y - q.y;
            float dz = m[k].z - q.z, dw = m[k].w - q.w;
            accm += dx * dx + dy * dy + dz * dz + dw * dw;
            q = ls[b * 64 + k * 16 + sub];
            dx = s[k].x - q.x; dy = s[k].y - q.y;
            dz = s[k].z - q.z; dw = s[k].w - q.w;
            accs += dx * dx + dy * dy + dz * dz + dw * dw;
        }
        am[b] = accm; as[b] = accs;
    }
    RS_STEP(8)
    RS_STEP(4)
    RS_STEP(2)
    RS_STEP(1)
    ws[OFF_DS + sub * SZ + e] = sqrtf(am[0]) + sqrtf(as[0]);
}

// fused top-k + goal: 1024 threads, values in registers, two-level histogram,
// single-wave shfl scans (barrier diet: ~10 __syncthreads total)
__global__ __launch_bounds__(1024) void k_topkgoal(const float* __restrict__ means,
                                                   const float* __restrict__ stds,
                                                   const float* __restrict__ t1p,
                                                   const float* __restrict__ t2p,
                                                   float* __restrict__ ws) {
    int b = blockIdx.x, tid = threadIdx.x;
    int lane = tid & 63, wid = tid >> 6;  // 16 waves
    const float4* ds4 = (const float4*)(ws + OFF_DS + b * SZ);

    __shared__ float wmn[16], wmx[16];
    __shared__ int hist[256], hist2[256];
    __shared__ float sh_lo, sh_sc;
    __shared__ int sh_T, sh_below, sh_T2, sh_cnt;
    __shared__ unsigned long long candK[512];
    __shared__ float topd_sh[TOPK];
    __shared__ int topi_sh[TOPK];
    __shared__ float w_sh[TOPK];
    __shared__ float mgp[4][256], sgp[4][256];

    // single global pass: 16 values per thread in registers
    float v[16];
    {
        float4 t0 = ds4[tid], t1 = ds4[tid + 1024], t2 = ds4[tid + 2048], t3 = ds4[tid + 3072];
        v[0] = t0.x; v[1] = t0.y; v[2] = t0.z; v[3] = t0.w;
        v[4] = t1.x; v[5] = t1.y; v[6] = t1.z; v[7] = t1.w;
        v[8] = t2.x; v[9] = t2.y; v[10] = t2.z; v[11] = t2.w;
        v[12] = t3.x; v[13] = t3.y; v[14] = t3.z; v[15] = t3.w;
    }

    float mn = v[0], mx = v[0];
#pragma unroll
    for (int i = 1; i < 16; i++) { mn = fminf(mn, v[i]); mx = fmaxf(mx, v[i]); }
#pragma unroll
    for (int off = 32; off > 0; off >>= 1) {
        mn = fminf(mn, __shfl_xor(mn, off, 64));
        mx = fmaxf(mx, __shfl_xor(mx, off, 64));
    }
    if (lane == 0) { wmn[wid] = mn; wmx[wid] = mx; }
    if (tid < 256) { hist[tid] = 0; hist2[tid] = 0; }
    if (tid == 0) sh_cnt = 0;
    __syncthreads();  // B1: wmn/wmx + zeroed hists visible
    if (wid == 0 && lane == 0) {
        float l = wmn[0], h = wmx[0];
#pragma unroll
        for (int i = 1; i < 16; i++) { l = fminf(l, wmn[i]); h = fmaxf(h, wmx[i]); }
        sh_lo = l;
        sh_sc = 255.0f / fmaxf(h - l, 1e-20f);
    }
    __syncthreads();  // B2
    float lo = sh_lo, sc = sh_sc;

    // coarse histogram (bins kept in registers)
    int bn[16];
#pragma unroll
    for (int i = 0; i < 16; i++) {
        bn[i] = min(max((int)((v[i] - lo) * sc), 0), 255);
        atomicAdd(&hist[bn[i]], 1);
    }
    __syncthreads();  // B3

    // wave-0 scan of hist + threshold crossing (no block barriers inside)
    if (wid == 0) {
        int a0 = hist[4 * lane], a1 = hist[4 * lane + 1];
        int a2 = hist[4 * lane + 2], a3 = hist[4 * lane + 3];
        a1 += a0; a2 += a1; a3 += a2;
        int tot = a3, run = tot;
#pragma unroll
        for (int off = 1; off < 64; off <<= 1) {
            int o = __shfl_up(run, off, 64);
            if (lane >= off) run += o;
        }
        int excl = run - tot;
        int c0 = a0 + excl, c1 = a1 + excl, c2 = a2 + excl, c3 = a3 + excl;
        int cc[4] = {c0, c1, c2, c3};
        int pp[4] = {excl, c0, c1, c2};
#pragma unroll
        for (int j = 0; j < 4; j++)
            if (cc[j] >= TOPK && pp[j] < TOPK) { sh_T = 4 * lane + j; sh_below = pp[j]; }
    }
    __syncthreads();  // B4
    int T = sh_T, below = sh_below;

    // fine histogram inside boundary bin T (fine bin recomputed, not stored)
    float flo = lo + (float)T / sc;
    float fsc = sc * 255.0f;
#pragma unroll
    for (int i = 0; i < 16; i++) {
        if (bn[i] == T) {
            int fb = min(max((int)((v[i] - flo) * fsc), 0), 255);
            atomicAdd(&hist2[fb], 1);
        }
    }
    __syncthreads();  // B5
    int need = TOPK - below;
    if (wid == 0) {
        int a0 = hist2[4 * lane], a1 = hist2[4 * lane + 1];
        int a2 = hist2[4 * lane + 2], a3 = hist2[4 * lane + 3];
        a1 += a0; a2 += a1; a3 += a2;
        int tot = a3, run = tot;
#pragma unroll
        for (int off = 1; off < 64; off <<= 1) {
            int o = __shfl_up(run, off, 64);
            if (lane >= off) run += o;
        }
        int excl = run - tot;
        int c0 = a0 + excl, c1 = a1 + excl, c2 = a2 + excl, c3 = a3 + excl;
        int cc[4] = {c0, c1, c2, c3};
        int pp[4] = {excl, c0, c1, c2};
#pragma unroll
        for (int j = 0; j < 4; j++)
            if (cc[j] >= need && pp[j] < need) sh_T2 = 4 * lane + j;
    }
    __syncthreads();  // B6
    int T2 = sh_T2;

    // collect candidates (value-prefix set, ~50-70 expected)
#pragma unroll
    for (int i = 0; i < 16; i++) {
        bool take = bn[i] < T;
        if (bn[i] == T) {
            int fb = min(max((int)((v[i] - flo) * fsc), 0), 255);
            take = (fb <= T2);
        }
        if (take) {
            int p = atomicAdd(&sh_cnt, 1);
            if (p < 512) {
                int idx = 4 * (tid + (i >> 2) * 1024) + (i & 3);
                candK[p] = ((unsigned long long)__float_as_uint(v[i]) << 32) | (unsigned int)idx;
            }
        }
    }
    __syncthreads();  // B7
    int cnt = min(sh_cnt, 512);

    // exact rank-count selection (key ties -> lowest index, matches jax)
    for (int p = tid; p < cnt; p += 1024) {
        unsigned long long kp = candK[p];
        int rank = 0;
        for (int q = 0; q < cnt; q++) rank += (candK[q] < kp) ? 1 : 0;
        if (rank < TOPK) {
            topd_sh[rank] = __uint_as_float((unsigned int)(kp >> 32));
            topi_sh[rank] = (int)(kp & 0xffffffffu);
        }
    }
    __syncthreads();  // B8

    // softmax(exp(-t1*d)) — exact double-exponential semantics
    float t1 = t1p[0], t2v = t2p[0];
    if (wid == 0) {
        float sv = (lane < TOPK) ? expf(-t1 * topd_sh[lane]) : -1e30f;
        float m = sv;
#pragma unroll
        for (int off = 32; off > 0; off >>= 1) m = fmaxf(m, __shfl_xor(m, off, 64));
        float e = (lane < TOPK) ? expf(sv - m) : 0.f;
        float sum = e;
#pragma unroll
        for (int off = 32; off > 0; off >>= 1) sum += __shfl_xor(sum, off, 64);
        if (lane < TOPK) w_sh[lane] = e / sum;
    }
    __syncthreads();  // B9

    // gather with all 16 waves: TOPK split across 4 quarters
    int d = tid & 255, qd = tid >> 8;
    float mg = 0.f, sg = 0.f;
    for (int r = qd; r < TOPK; r += 4) {
        float w = w_sh[r];
        int idx = topi_sh[r];
        mg += w * means[(size_t)idx * DIM + d];
        sg += w * stds[(size_t)idx * DIM + d];
    }
    mgp[qd][d] = mg; sgp[qd][d] = sg;
    __syncthreads();  // B10
    if (tid < 256) {
        float MG = mgp[0][tid] + mgp[1][tid] + mgp[2][tid] + mgp[3][tid];
        float SG = sgp[0][tid] + sgp[1][tid] + sgp[2][tid] + sgp[3][tid];
        float mean = ws[OFF_MEANB + b * DIM + tid];
        float sd = ws[OFF_STDB + b * DIM + tid];
        float lerp = 1.f / (1.f + expf(-t2v));
        float mf = lerp * MG + (1.f - lerp) * mean;
        float sf = lerp * SG + (1.f - lerp) * sd;
        float A = sf / sd;
        float C = mf - A * mean;
        ws[OFF_A + b * DIM + tid] = A;
        ws[OFF_C + b * DIM + tid] = C;
    }
}

__global__ __launch_bounds__(256) void k_apply(const float* __restrict__ x,
                                               const float* __restrict__ ws,
                                               float* __restrict__ out) {
    int f4 = blockIdx.x * 256 + threadIdx.x;
    int b = f4 >> 17;
    int d4 = f4 & 63;
    float4 xv = ((const float4*)x)[f4];
    float4 a = ((const float4*)(ws + OFF_A))[b * 64 + d4];
    float4 c = ((const float4*)(ws + OFF_C))[b * 64 + d4];
    float4 o;
    o.x = fmaf(a.x, xv.x, c.x);
    o.y = fmaf(a.y, xv.y, c.y);
    o.z = fmaf(a.z, xv.z, c.z);
    o.w = fmaf(a.w, xv.w, c.w);
    ((float4*)out)[f4] = o;
}

extern "C" void kernel_launch(void* const* d_in, const int* in_sizes, int n_in,
                              void* d_out, int out_size, void* d_ws, size_t ws_size,
                              hipStream_t stream) {
    const float* x = (const float*)d_in[0];
    const float* means = (const float*)d_in[1];
    const float* stds = (const float*)d_in[2];
    const float* t1 = (const float*)d_in[3];
    const float* t2 = (const float*)d_in[4];
    float* out = (float*)d_out;
    float* ws = (float*)d_ws;

    k_partial<<<dim3(NCHUNK, B), 256, 0, stream>>>(x, ws);
    k_finalize<<<B, 256, 0, stream>>>(ws);
    k_dist<<<SZ / 16, 256, 0, stream>>>(means, stds, ws);
    k_topkgoal<<<B, 1024, 0, stream>>>(means, stds, t1, t2, ws);
    k_apply<<<(B * NN * DIM / 4) / 256, 256, 0, stream>>>(x, ws, out);
}